// Round 1
// baseline (173.119 us; speedup 1.0000x reference)
//
#include <hip/hip_runtime.h>
#include <math.h>

// ---------------------------------------------------------------------------
// QConv2dMedium: quantum conv = per-pixel 16-ch map
//   out[k] = clip(8 * |U[k,0:9] . p|^2 / max(||p||,1e-12)^2, 0, 1)
// U = (CNOT perms L1)(Layer1)(CNOT perms L0)(Layer0), 16x16 complex.
// ---------------------------------------------------------------------------

#define WIRES 4
#define DIM 16

// Rot(phi, theta, omega) entry [rb][cb] of wire i's 2x2, as complex (er, ei)
__device__ inline void rot_entry(float phi, float th, float om, int rb, int cb,
                                 float& er, float& ei) {
    float a = 0.5f * (phi + om);
    float b = 0.5f * (phi - om);
    float cc = cosf(0.5f * th), ss = sinf(0.5f * th);
    if (rb == 0 && cb == 0) { er = cc * cosf(a); ei = -cc * sinf(a); }
    else if (rb == 0 && cb == 1) { er = -ss * cosf(b); ei = -ss * sinf(b); }
    else if (rb == 1 && cb == 0) { er = ss * cosf(b); ei = -ss * sinf(b); }
    else { er = cc * cosf(a); ei = cc * sinf(a); }
}

// layer element L[r][c] = prod_i R_i[bit_i(r)][bit_i(c)], bit_i = bit (3-i)
__device__ inline void layer_elem(const float* __restrict__ w, int l, int r,
                                  int c, float& pr, float& pi) {
    pr = 1.f; pi = 0.f;
    #pragma unroll
    for (int i = 0; i < WIRES; ++i) {
        const float* wi = w + (l * WIRES + i) * 3;
        float er, ei;
        int rb = (r >> (3 - i)) & 1, cb = (c >> (3 - i)) & 1;
        rot_entry(wi[0], wi[1], wi[2], rb, cb, er, ei);
        float nr = pr * er - pi * ei;
        float ni = pr * ei + pi * er;
        pr = nr; pi = ni;
    }
}

// source row after applying the layer-l CNOT chain (dest row r reads src row)
__device__ inline int cnot_src(int r, int range) {
    int src = r;
    // U_final[j] = U[p0(p1(p2(p3(j))))] -> apply p3 first
    #pragma unroll
    for (int i = WIRES - 1; i >= 0; --i) {
        int control = i, target = (i + range) & 3;
        int cbit = 1 << (3 - control), tbit = 1 << (3 - target);
        if (src & cbit) src ^= tbit;
    }
    return src;
}

__global__ __launch_bounds__(256) void build_unitary(
        const float* __restrict__ w, float* __restrict__ uout) {
    __shared__ float Lr[DIM][DIM], Li[DIM][DIM];
    __shared__ float Ur[DIM][DIM], Ui[DIM][DIM];
    __shared__ float Tr[DIM][DIM], Ti[DIM][DIM];
    int t = threadIdx.x;
    int r = t >> 4, c = t & 15;

    // ---- layer 0 (U starts as identity, so U = L0) ----
    float lr, li;
    layer_elem(w, 0, r, c, lr, li);
    Lr[r][c] = lr; Li[r][c] = li;
    __syncthreads();
    // CNOT perms, range = 0 % 3 + 1 = 1
    int s0 = cnot_src(r, 1);
    Ur[r][c] = Lr[s0][c]; Ui[r][c] = Li[s0][c];
    __syncthreads();

    // ---- layer 1: T = L1 @ U ----
    layer_elem(w, 1, r, c, lr, li);
    Lr[r][c] = lr; Li[r][c] = li;
    __syncthreads();
    float ar = 0.f, ai = 0.f;
    #pragma unroll
    for (int m = 0; m < DIM; ++m) {
        float xr = Lr[r][m], xi = Li[r][m];
        float yr = Ur[m][c], yi = Ui[m][c];
        ar += xr * yr - xi * yi;
        ai += xr * yi + xi * yr;
    }
    Tr[r][c] = ar; Ti[r][c] = ai;
    __syncthreads();
    // CNOT perms, range = 1 % 3 + 1 = 2
    int s1 = cnot_src(r, 2);
    uout[r * DIM + c]           = Tr[s1][c];
    uout[256 + r * DIM + c]     = Ti[s1][c];
}

#define H 256
#define W 256
#define NB 32
#define OUTC 16

__global__ __launch_bounds__(256) void qconv_kernel(
        const float* __restrict__ x, const float* __restrict__ u,
        float* __restrict__ out) {
    __shared__ float sUr[OUTC][9];
    __shared__ float sUi[OUTC][9];
    __shared__ float rows[3][W + 8];   // cols 0..257 map to j-1..256

    int t = threadIdx.x;
    int blk = blockIdx.x;          // 0 .. NB*H-1
    int i = blk & (H - 1);
    int b = blk >> 8;

    if (t < OUTC * 9) {
        int k = t / 9, m = t % 9;
        sUr[k][m] = u[k * DIM + m];
        sUi[k][m] = u[256 + k * DIM + m];
    }

    const float* xb = x + (size_t)b * H * W;
    #pragma unroll
    for (int di = 0; di < 3; ++di) {
        int row = i + di - 1;
        for (int cpos = t; cpos < W + 2; cpos += 256) {
            int j = cpos - 1;
            float v = 0.01f;
            if ((unsigned)row < (unsigned)H && (unsigned)j < (unsigned)W)
                v = xb[row * W + j];
            rows[di][cpos] = v;
        }
    }
    __syncthreads();

    float p[9];
    #pragma unroll
    for (int di = 0; di < 3; ++di)
        #pragma unroll
        for (int dj = 0; dj < 3; ++dj)
            p[di * 3 + dj] = rows[di][t + dj];

    float n2 = 0.f;
    #pragma unroll
    for (int m = 0; m < 9; ++m) n2 = fmaf(p[m], p[m], n2);
    // (DIM*0.5)/max(||p||,1e-12)^2 ; max(n,e)^2 == max(n^2, e^2) for n>=0
    float factor = 8.0f / fmaxf(n2, 1e-24f);

    float* ob = out + (size_t)b * OUTC * H * W + (size_t)i * W + t;
    #pragma unroll
    for (int k = 0; k < OUTC; ++k) {
        float sr = 0.f, si = 0.f;
        #pragma unroll
        for (int m = 0; m < 9; ++m) {
            sr = fmaf(sUr[k][m], p[m], sr);   // broadcast LDS read: free
            si = fmaf(sUi[k][m], p[m], si);
        }
        float v = factor * (sr * sr + si * si);
        ob[(size_t)k * H * W] = fminf(v, 1.0f);
    }
}

extern "C" void kernel_launch(void* const* d_in, const int* in_sizes, int n_in,
                              void* d_out, int out_size, void* d_ws, size_t ws_size,
                              hipStream_t stream) {
    const float* x = (const float*)d_in[0];        // (32,1,256,256) fp32
    const float* w = (const float*)d_in[1];        // (2,4,3) fp32
    float* out = (float*)d_out;                    // (32,16,256,256) fp32
    float* uws = (float*)d_ws;                     // 512 floats: Re | Im

    build_unitary<<<1, 256, 0, stream>>>(w, uws);
    qconv_kernel<<<NB * H, 256, 0, stream>>>(x, uws, out);
}